// Round 9
// baseline (492.491 us; speedup 1.0000x reference)
//
#include <hip/hip_runtime.h>
#include <hip/hip_bf16.h>

#define NUM_GRAPHS 1024
#define NCLS 10
#define BN_EPS 1e-5f
#define SLOPE 0.01f
#define PB 256             // scatter partition blocks
#define WN 64              // nodes per window
#define CAP 1280           // edge capacity per window (mean 1024 + 8 sigma)
#define NBMAX 1600         // max windows (N <= 102400)

typedef __attribute__((ext_vector_type(8))) short          bfrag;
typedef __attribute__((ext_vector_type(4))) float          ffrag;
typedef __attribute__((ext_vector_type(8))) unsigned short ushort8;

__device__ __forceinline__ float leaky(float v) { return v > 0.f ? v : SLOPE * v; }

__device__ __forceinline__ unsigned short f2bf(float f) {
    unsigned int u = __float_as_uint(f);
    unsigned int r = (u + 0x7fffu + ((u >> 16) & 1u)) >> 16;
    return (unsigned short)r;
}
__device__ __forceinline__ float bf2f(unsigned short u) {
    return __uint_as_float(((unsigned int)u) << 16);
}

// async global->LDS, 16B per lane; LDS dst is wave-uniform base + lane*16
__device__ __forceinline__ void load_lds16(const void* g, void* l) {
    __builtin_amdgcn_global_load_lds((const __attribute__((address_space(1))) void*)g,
                                     (__attribute__((address_space(3))) void*)l, 16, 0, 0);
}

// ============ fused scatter + conversions ======================================
// blocks [0,PB): two-pass window sort of edges -> packedE[(dst>>6)*CAP + slot]
// blocks [PB,PB+4): weight transpose+cvt; rest: x -> bf16
__global__ __launch_bounds__(256)
void scatter_cvt_kernel(const int* __restrict__ src, const int* __restrict__ dst,
                        int* __restrict__ cursor, int* __restrict__ packedE,
                        int E, int chunk, int NB,
                        const float* __restrict__ x, unsigned short* __restrict__ xb, int nX,
                        const float* __restrict__ W0, const float* __restrict__ W1,
                        const float* __restrict__ W2, const float* __restrict__ W3,
                        unsigned short* __restrict__ WT)
{
    int b = blockIdx.x;
    int t = threadIdx.x;
    if (b < PB) {
        __shared__ int h[NBMAX];
        __shared__ int base[NBMAX];
        for (int i = t; i < NB; i += 256) h[i] = 0;
        __syncthreads();
        int e0 = b * chunk;
        int e1 = min(E, e0 + chunk);
        for (int e = e0 + t; e < e1; e += 256)
            atomicAdd(&h[dst[e] >> 6], 1);
        __syncthreads();
        for (int i = t; i < NB; i += 256) {
            int c = h[i];
            base[i] = c ? atomicAdd(&cursor[i], c) : 0;
            h[i] = 0;
        }
        __syncthreads();
        for (int e = e0 + t; e < e1; e += 256) {
            int d = dst[e];
            int s = src[e];
            int bk = d >> 6;
            int off = atomicAdd(&h[bk], 1) + base[bk];
            if (off < CAP) packedE[bk * CAP + off] = (s << 6) | (d & 63);
        }
        return;
    }
    b -= PB;
    if (b < 4) {
        const float* W = (b == 0) ? W0 : (b == 1) ? W1 : (b == 2) ? W2 : W3;
        unsigned short* O = WT + (size_t)b * 16384;
#pragma unroll
        for (int p = 0; p < 64; ++p) {
            int idx = p * 256 + t;
            int n = idx >> 7, k = idx & 127;
            O[n * 128 + k] = f2bf(W[k * 128 + n]);
        }
        return;
    }
    b -= 4;
    int i = (b * 256 + t) * 4;
    if (i + 3 < nX) {
        float4 f = *(const float4*)&x[i];
        unsigned short o0 = f2bf(f.x), o1 = f2bf(f.y), o2 = f2bf(f.z), o3 = f2bf(f.w);
        unsigned long long packed = (unsigned long long)o0 | ((unsigned long long)o1 << 16)
                                  | ((unsigned long long)o2 << 32) | ((unsigned long long)o3 << 48);
        *(unsigned long long*)&xb[i] = packed;
    } else if (i < nX) {
        for (int j = i; j < nX; ++j) xb[j] = f2bf(x[j]);
    }
}

// ============ gather per 64-node window (in-LDS CSR, register accumulate) =======
// out[i] = f( X[i] + sum_{j->i} X[j] ),  f = identity or inline-BN affine
template<bool AFFINE>
__global__ __launch_bounds__(256)
void gather_win(const unsigned short* __restrict__ X, const int* __restrict__ cursor,
                const int* __restrict__ packedE,
                const float* __restrict__ bnsum, const float* __restrict__ bnsq,
                const float* __restrict__ g, const float* __restrict__ be,
                unsigned short* __restrict__ out, int N)
{
    __shared__ int   raw[CAP];
    __shared__ int   lst[CAP];
    __shared__ int   hist[WN];
    __shared__ int   offs[WN];
    __shared__ int   cur[WN];
    __shared__ float Af[128], Bf[128];

    const int k = blockIdx.x;
    const int t = threadIdx.x;

    if (t < WN) hist[t] = 0;
    if (AFFINE && t < 128) {
        float invN = 1.f / (float)N;
        float mean = bnsum[t] * invN;
        float var  = bnsq[t] * invN - mean * mean;
        float a = g[t] * rsqrtf(var + BN_EPS);
        Af[t] = a;
        Bf[t] = be[t] - a * mean;
    }
    __syncthreads();

    int cnt = cursor[k];
    if (cnt > CAP) cnt = CAP;
    const int* pe = packedE + (size_t)k * CAP;
    for (int i = t; i < cnt; i += 256) {
        int p = pe[i];
        raw[i] = p;
        atomicAdd(&hist[p & 63], 1);
    }
    __syncthreads();
    if (t < 64) {
        int v = hist[t];
        int x = v;
#pragma unroll
        for (int off = 1; off < 64; off <<= 1) {
            int y = __shfl_up(x, off, 64);
            if (t >= off) x += y;
        }
        offs[t] = x - v;
        cur[t]  = x - v;
    }
    __syncthreads();
    for (int i = t; i < cnt; i += 256) {
        int p = raw[i];
        int slot = atomicAdd(&cur[p & 63], 1);
        lst[slot] = p >> 6;
    }
    __syncthreads();

    const int grp = t >> 4;
    const int c8  = (t & 15) * 8;
#pragma unroll
    for (int pass = 0; pass < 4; ++pass) {
        int n = pass * 16 + grp;
        int node = k * WN + n;
        if (node >= N) continue;
        float acc[8];
        {
            ushort8 xv = *(const ushort8*)&X[(size_t)node * 128 + c8];
#pragma unroll
            for (int j = 0; j < 8; ++j) acc[j] = bf2f(xv[j]);
        }
        int s0 = offs[n];
        int dg = hist[n];
        int s1 = s0 + dg;
        int i = s0;
        for (; i + 1 < s1; i += 2) {
            int j0 = lst[i], j1 = lst[i + 1];
            ushort8 u0 = *(const ushort8*)&X[(size_t)j0 * 128 + c8];
            ushort8 u1 = *(const ushort8*)&X[(size_t)j1 * 128 + c8];
#pragma unroll
            for (int j = 0; j < 8; ++j) acc[j] += bf2f(u0[j]) + bf2f(u1[j]);
        }
        if (i < s1) {
            int j0 = lst[i];
            ushort8 u0 = *(const ushort8*)&X[(size_t)j0 * 128 + c8];
#pragma unroll
            for (int j = 0; j < 8; ++j) acc[j] += bf2f(u0[j]);
        }
        ushort8 o;
        if (AFFINE) {
            float cf = (float)(dg + 1);
#pragma unroll
            for (int j = 0; j < 8; ++j)
                o[j] = f2bf(fmaf(Af[c8 + j], acc[j], cf * Bf[c8 + j]));
        } else {
#pragma unroll
            for (int j = 0; j < 8; ++j) o[j] = f2bf(acc[j]);
        }
        *(ushort8*)&out[(size_t)node * 128 + c8] = o;
    }
}

// ================= MFMA GEMM v3: Out = bf16(leaky(A @ W + bias)) ================
// Both tiles staged direct-to-LDS via global_load_lds width=16. The XOR swizzle
// lives in the SOURCE address (lane loads the chunk belonging at its fixed LDS
// slot), so LDS frag reads stay conflict-free. OOB rows read a 16B zero pad.
template<bool STATS>
__global__ __launch_bounds__(256)
void gemm_mfma(const unsigned short* __restrict__ A, const unsigned short* __restrict__ WT,
               const float* __restrict__ bias, unsigned short* __restrict__ Out,
               float* __restrict__ stat_sum, float* __restrict__ stat_sq,
               const unsigned short* __restrict__ zeroPad, int N)
{
    __shared__ unsigned short As[128 * 128];  // 32 KB, slot (r,g'): holds chunk g'^(r&7)
    __shared__ unsigned short Ws[128 * 128];  // 32 KB, same layout
    __shared__ float sred[256];

    const int t = threadIdx.x;
    const int row0 = blockIdx.x * 128;

#pragma unroll
    for (int p = 0; p < 8; ++p) {
        int s  = p * 256 + t;          // LDS slot; per wave: uniform base + lane*16B
        int r  = s >> 4;
        int gp = s & 15;
        int g  = gp ^ (r & 7);         // source chunk for this slot
        int gr = row0 + r;
        const unsigned short* ga = (gr < N) ? &A[(size_t)gr * 128 + g * 8] : zeroPad;
        load_lds16(ga, &As[s * 8]);
        load_lds16(&WT[r * 128 + g * 8], &Ws[s * 8]);
    }
    __syncthreads();

    const int wave = t >> 6;
    const int lane = t & 63;
    const int m    = lane & 15;
    const int quad = lane >> 4;

    ffrag acc[2][8];
#pragma unroll
    for (int rt = 0; rt < 2; ++rt)
#pragma unroll
        for (int ct = 0; ct < 8; ++ct) {
            ffrag z = {0.f, 0.f, 0.f, 0.f};
            acc[rt][ct] = z;
        }

#pragma unroll
    for (int ks = 0; ks < 4; ++ks) {
        int kc = ks * 4 + quad;
        bfrag b[8];
#pragma unroll
        for (int ct = 0; ct < 8; ++ct) {
            int n = ct * 16 + m;
            b[ct] = *(const bfrag*)&Ws[(n * 16 + (kc ^ (n & 7))) * 8];
        }
        bfrag a0, a1;
        {
            int r = wave * 32 + m;
            a0 = *(const bfrag*)&As[(r * 16 + (kc ^ (r & 7))) * 8];
        }
        {
            int r = wave * 32 + 16 + m;
            a1 = *(const bfrag*)&As[(r * 16 + (kc ^ (r & 7))) * 8];
        }
#pragma unroll
        for (int ct = 0; ct < 8; ++ct) {
            acc[0][ct] = __builtin_amdgcn_mfma_f32_16x16x32_bf16(a0, b[ct], acc[0][ct], 0, 0, 0);
            acc[1][ct] = __builtin_amdgcn_mfma_f32_16x16x32_bf16(a1, b[ct], acc[1][ct], 0, 0, 0);
        }
    }

    float bv[8];
#pragma unroll
    for (int ct = 0; ct < 8; ++ct) bv[ct] = bias[ct * 16 + m];

    float colsum[8], colsq[8];
#pragma unroll
    for (int ct = 0; ct < 8; ++ct) { colsum[ct] = 0.f; colsq[ct] = 0.f; }

    __syncthreads();   // done with tiles; reuse As as transpose buffer
    unsigned short* tw = &As[wave * 32 * 128];   // this wave's 32x128 region
#pragma unroll
    for (int rt = 0; rt < 2; ++rt) {
#pragma unroll
        for (int reg = 0; reg < 4; ++reg) {
            int rl = rt * 16 + quad * 4 + reg;
            bool valid = (row0 + wave * 32 + rl) < N;
#pragma unroll
            for (int ct = 0; ct < 8; ++ct) {
                float v = leaky(acc[rt][ct][reg] + bv[ct]);
                tw[rl * 128 + ct * 16 + m] = f2bf(v);
                if (STATS && valid) { colsum[ct] += v; colsq[ct] += v * v; }
            }
        }
    }
    __syncthreads();
#pragma unroll
    for (int p = 0; p < 8; ++p) {
        int li = p * 64 + lane;        // 0..511 over this wave's region
        int rl = li >> 4;              // 0..31
        int cg = (li & 15) * 8;
        int r = row0 + wave * 32 + rl;
        if (r < N)
            *(ushort8*)&Out[(size_t)r * 128 + cg] = *(const ushort8*)&tw[rl * 128 + cg];
    }

    if (STATS) {
        __syncthreads();
        if (t < 128) { sred[t] = 0.f; sred[128 + t] = 0.f; }
        __syncthreads();
#pragma unroll
        for (int ct = 0; ct < 8; ++ct) {
            atomicAdd(&sred[ct * 16 + m], colsum[ct]);
            atomicAdd(&sred[128 + ct * 16 + m], colsq[ct]);
        }
        __syncthreads();
        if (t < 128) {
            atomicAdd(&stat_sum[t], sred[t]);
            atomicAdd(&stat_sq[t], sred[128 + t]);
        }
    }
}

// ================= pool + head (inline BN2 finalize) ============================
__device__ __forceinline__ int lower_bound(const int* b, int n, int v)
{
    int lo = 0, hi = n;
    while (lo < hi) { int mid = (lo + hi) >> 1; if (b[mid] < v) lo = mid + 1; else hi = mid; }
    return lo;
}

__global__ __launch_bounds__(128)
void pool_head(const unsigned short* __restrict__ Hn, const int* __restrict__ batch,
               const float* __restrict__ bnsum, const float* __restrict__ bnsq,
               const float* __restrict__ g2, const float* __restrict__ be2,
               const float* __restrict__ fcW1, const float* __restrict__ fcb1,
               const float* __restrict__ fcW2, const float* __restrict__ fcb2,
               float* __restrict__ out, int N)
{
    int g = blockIdx.x;
    int t = threadIdx.x;
    __shared__ int bounds[2];
    __shared__ float row[128];
    __shared__ float z1[128];
    if (t < 2) bounds[t] = lower_bound(batch, N, g + t);
    float invN = 1.f / (float)N;
    float mean = bnsum[t] * invN;
    float var  = bnsq[t] * invN - mean * mean;
    float a2 = g2[t] * rsqrtf(var + BN_EPS);
    float b2 = be2[t] - a2 * mean;
    __syncthreads();
    int ss = bounds[0], se = bounds[1];
    float acc = 0.f;
    for (int i = ss; i < se; ++i) acc += bf2f(Hn[(size_t)i * 128 + t]);
    float cnt = (float)(se - ss);
    row[t] = fmaf(a2, acc, cnt * b2);
    __syncthreads();
    float a1 = fcb1[t];
#pragma unroll 8
    for (int k = 0; k < 128; ++k) a1 = fmaf(row[k], fcW1[(size_t)k * 128 + t], a1);
    z1[t] = leaky(a1);
    __syncthreads();
    if (t < 64) {
        float lg[NCLS];
#pragma unroll
        for (int c = 0; c < NCLS; ++c) {
            float p = z1[t] * fcW2[t * NCLS + c] + z1[t + 64] * fcW2[(t + 64) * NCLS + c];
#pragma unroll
            for (int off = 32; off > 0; off >>= 1) p += __shfl_down(p, off, 64);
            if (t == 0) lg[c] = p + fcb2[c];
        }
        if (t == 0) {
            float m = lg[0];
#pragma unroll
            for (int c = 1; c < NCLS; ++c) m = fmaxf(m, lg[c]);
            float s = 0.f;
#pragma unroll
            for (int c = 0; c < NCLS; ++c) s += expf(lg[c] - m);
            float lse = logf(s);
#pragma unroll
            for (int c = 0; c < NCLS; ++c) out[(size_t)g * NCLS + c] = lg[c] - m - lse;
        }
    }
}

// ================= launch =======================================================
extern "C" void kernel_launch(void* const* d_in, const int* in_sizes, int n_in,
                              void* d_out, int out_size, void* d_ws, size_t ws_size,
                              hipStream_t stream)
{
    const float* x    = (const float*)d_in[0];
    const float* W1a  = (const float*)d_in[1];
    const float* b1a  = (const float*)d_in[2];
    const float* W1b  = (const float*)d_in[3];
    const float* b1b  = (const float*)d_in[4];
    const float* g1   = (const float*)d_in[5];
    const float* be1  = (const float*)d_in[6];
    const float* W2a  = (const float*)d_in[7];
    const float* b2a  = (const float*)d_in[8];
    const float* W2b  = (const float*)d_in[9];
    const float* b2b  = (const float*)d_in[10];
    const float* g2   = (const float*)d_in[11];
    const float* be2  = (const float*)d_in[12];
    const float* fcW1 = (const float*)d_in[13];
    const float* fcb1 = (const float*)d_in[14];
    const float* fcW2 = (const float*)d_in[15];
    const float* fcb2 = (const float*)d_in[16];
    const int*   edge = (const int*)d_in[17];
    const int*   batch= (const int*)d_in[18];

    const int N = in_sizes[0] / 128;
    const int E = in_sizes[17] / 2;
    const int* src = edge;
    const int* dst = edge + E;
    const size_t NH = (size_t)N * 128;
    const int NB = (N + WN - 1) / WN;       // 64-node windows (<= NBMAX)
    const int chunk = (E + PB - 1) / PB;

    int*   cursor = (int*)d_ws;                     // 2048 ints
    float* stats  = (float*)(cursor + 2048);        // 512 floats
    float* sum1   = stats;
    float* sq1    = stats + 128;
    float* sum2   = stats + 256;
    float* sq2    = stats + 384;
    unsigned short* zeroPad = (unsigned short*)(stats + 512);  // 32 B zeros
    int*   packedE = (int*)(stats + 520);           // NBMAX*CAP ints (~8 MB)
    unsigned short* xb   = (unsigned short*)(packedE + ((size_t)NBMAX * CAP));
    unsigned short* bufA = xb + NH;
    unsigned short* bufB = bufA + NH;
    unsigned short* wt   = bufB + NH;               // 4 x 16384 bf16, transposed
    unsigned short* wt1a = wt;
    unsigned short* wt1b = wt + 16384;
    unsigned short* wt2a = wt + 32768;
    unsigned short* wt2b = wt + 49152;

    const int cvtBlocks  = (int)((NH / 4 + 255) / 256);
    const int gemmBlocks = (N + 127) / 128;

    hipMemsetAsync(d_ws, 0, 2048 * sizeof(int) + 520 * sizeof(float), stream);

    // fused: window-sort edges + x/weight bf16 conversion
    scatter_cvt_kernel<<<PB + 4 + cvtBlocks, 256, 0, stream>>>(
        src, dst, cursor, packedE, E, chunk, NB,
        x, xb, (int)NH, W1a, W1b, W2a, W2b, wt);

    // conv1
    gather_win<false><<<NB, 256, 0, stream>>>(xb, cursor, packedE,
                                              nullptr, nullptr, nullptr, nullptr, bufA, N);
    gemm_mfma<false><<<gemmBlocks, 256, 0, stream>>>(bufA, wt1a, b1a, bufB,
                                                     nullptr, nullptr, zeroPad, N);
    gemm_mfma<true><<<gemmBlocks, 256, 0, stream>>>(bufB, wt1b, b1b, bufA,
                                                    sum1, sq1, zeroPad, N);

    // conv2 (BN1 finalized inline in gather epilogue)
    gather_win<true><<<NB, 256, 0, stream>>>(bufA, cursor, packedE,
                                             sum1, sq1, g1, be1, bufB, N);
    gemm_mfma<false><<<gemmBlocks, 256, 0, stream>>>(bufB, wt2a, b2a, bufA,
                                                     nullptr, nullptr, zeroPad, N);
    gemm_mfma<true><<<gemmBlocks, 256, 0, stream>>>(bufA, wt2b, b2b, bufB,
                                                    sum2, sq2, zeroPad, N);

    // pool (BN2 finalized inline) + head
    pool_head<<<NUM_GRAPHS, 128, 0, stream>>>(bufB, batch, sum2, sq2, g2, be2,
                                              fcW1, fcb1, fcW2, fcb2, (float*)d_out, N);
}

// Round 10
// 434.109 us; speedup vs baseline: 1.1345x; 1.1345x over previous
//
#include <hip/hip_runtime.h>
#include <hip/hip_bf16.h>

#define NUM_GRAPHS 1024
#define NCLS 10
#define BN_EPS 1e-5f
#define SLOPE 0.01f
#define PB 256             // scatter partition blocks
#define WN 64              // nodes per window
#define CAP 1280           // edge capacity per window (mean 1024 + 8 sigma)
#define NBMAX 1600         // max windows (N <= 102400)

typedef __attribute__((ext_vector_type(8))) short          bfrag;
typedef __attribute__((ext_vector_type(4))) float          ffrag;
typedef __attribute__((ext_vector_type(8))) unsigned short ushort8;

__device__ __forceinline__ float leaky(float v) { return v > 0.f ? v : SLOPE * v; }

__device__ __forceinline__ unsigned short f2bf(float f) {
    unsigned int u = __float_as_uint(f);
    unsigned int r = (u + 0x7fffu + ((u >> 16) & 1u)) >> 16;
    return (unsigned short)r;
}
__device__ __forceinline__ float bf2f(unsigned short u) {
    return __uint_as_float(((unsigned int)u) << 16);
}

// async global->LDS, 16B per lane; LDS dst is wave-uniform base + lane*16
__device__ __forceinline__ void load_lds16(const void* g, void* l) {
    __builtin_amdgcn_global_load_lds((const __attribute__((address_space(1))) void*)g,
                                     (__attribute__((address_space(3))) void*)l, 16, 0, 0);
}

// ============ fused scatter + conversions ======================================
// blocks [0,PB): two-pass window sort of edges -> packedE[(dst>>6)*CAP + slot]
// blocks [PB,PB+4): weight transpose+cvt; rest: x -> bf16
__global__ __launch_bounds__(256)
void scatter_cvt_kernel(const int* __restrict__ src, const int* __restrict__ dst,
                        int* __restrict__ cursor, int* __restrict__ packedE,
                        int E, int chunk, int NB,
                        const float* __restrict__ x, unsigned short* __restrict__ xb, int nX,
                        const float* __restrict__ W0, const float* __restrict__ W1,
                        const float* __restrict__ W2, const float* __restrict__ W3,
                        unsigned short* __restrict__ WT)
{
    int b = blockIdx.x;
    int t = threadIdx.x;
    if (b < PB) {
        __shared__ int h[NBMAX];
        __shared__ int base[NBMAX];
        for (int i = t; i < NB; i += 256) h[i] = 0;
        __syncthreads();
        int e0 = b * chunk;
        int e1 = min(E, e0 + chunk);
        for (int e = e0 + t; e < e1; e += 256)
            atomicAdd(&h[dst[e] >> 6], 1);
        __syncthreads();
        for (int i = t; i < NB; i += 256) {
            int c = h[i];
            base[i] = c ? atomicAdd(&cursor[i], c) : 0;
            h[i] = 0;
        }
        __syncthreads();
        for (int e = e0 + t; e < e1; e += 256) {
            int d = dst[e];
            int s = src[e];
            int bk = d >> 6;
            int off = atomicAdd(&h[bk], 1) + base[bk];
            if (off < CAP) packedE[bk * CAP + off] = (s << 6) | (d & 63);
        }
        return;
    }
    b -= PB;
    if (b < 4) {
        const float* W = (b == 0) ? W0 : (b == 1) ? W1 : (b == 2) ? W2 : W3;
        unsigned short* O = WT + (size_t)b * 16384;
#pragma unroll
        for (int p = 0; p < 64; ++p) {
            int idx = p * 256 + t;
            int n = idx >> 7, k = idx & 127;
            O[n * 128 + k] = f2bf(W[k * 128 + n]);
        }
        return;
    }
    b -= 4;
    int i = (b * 256 + t) * 4;
    if (i + 3 < nX) {
        float4 f = *(const float4*)&x[i];
        unsigned short o0 = f2bf(f.x), o1 = f2bf(f.y), o2 = f2bf(f.z), o3 = f2bf(f.w);
        unsigned long long packed = (unsigned long long)o0 | ((unsigned long long)o1 << 16)
                                  | ((unsigned long long)o2 << 32) | ((unsigned long long)o3 << 48);
        *(unsigned long long*)&xb[i] = packed;
    } else if (i < nX) {
        for (int j = i; j < nX; ++j) xb[j] = f2bf(x[j]);
    }
}

// ============ gather: 2 blocks per 64-node window (in-LDS CSR) ==================
// out[i] = f( X[i] + sum_{j->i} X[j] ),  f = identity or inline-BN affine
// blockIdx = window*2 + half; each block builds the window CSR, gathers 32 nodes.
template<bool AFFINE>
__global__ __launch_bounds__(256)
void gather_win(const unsigned short* __restrict__ X, const int* __restrict__ cursor,
                const int* __restrict__ packedE,
                const float* __restrict__ bnsum, const float* __restrict__ bnsq,
                const float* __restrict__ g, const float* __restrict__ be,
                unsigned short* __restrict__ out, int N)
{
    __shared__ int   raw[CAP];
    __shared__ int   lst[CAP];
    __shared__ int   hist[WN];
    __shared__ int   offs[WN];
    __shared__ int   cur[WN];
    __shared__ float Af[128], Bf[128];

    const int k    = blockIdx.x >> 1;   // window
    const int half = blockIdx.x & 1;    // which 32 nodes
    const int t = threadIdx.x;

    if (t < WN) hist[t] = 0;
    if (AFFINE && t < 128) {
        float invN = 1.f / (float)N;
        float mean = bnsum[t] * invN;
        float var  = bnsq[t] * invN - mean * mean;
        float a = g[t] * rsqrtf(var + BN_EPS);
        Af[t] = a;
        Bf[t] = be[t] - a * mean;
    }
    __syncthreads();

    int cnt = cursor[k];
    if (cnt > CAP) cnt = CAP;
    const int* pe = packedE + (size_t)k * CAP;
    for (int i = t; i < cnt; i += 256) {
        int p = pe[i];
        raw[i] = p;
        atomicAdd(&hist[p & 63], 1);
    }
    __syncthreads();
    if (t < 64) {
        int v = hist[t];
        int x = v;
#pragma unroll
        for (int off = 1; off < 64; off <<= 1) {
            int y = __shfl_up(x, off, 64);
            if (t >= off) x += y;
        }
        offs[t] = x - v;
        cur[t]  = x - v;
    }
    __syncthreads();
    for (int i = t; i < cnt; i += 256) {
        int p = raw[i];
        int slot = atomicAdd(&cur[p & 63], 1);
        lst[slot] = p >> 6;
    }
    __syncthreads();

    const int grp = t >> 4;
    const int c8  = (t & 15) * 8;
#pragma unroll
    for (int pass = 0; pass < 2; ++pass) {
        int n = half * 32 + pass * 16 + grp;
        int node = k * WN + n;
        if (node >= N) continue;
        float acc[8];
        {
            ushort8 xv = *(const ushort8*)&X[(size_t)node * 128 + c8];
#pragma unroll
            for (int j = 0; j < 8; ++j) acc[j] = bf2f(xv[j]);
        }
        int s0 = offs[n];
        int dg = hist[n];
        int s1 = s0 + dg;
        int i = s0;
        for (; i + 1 < s1; i += 2) {
            int j0 = lst[i], j1 = lst[i + 1];
            ushort8 u0 = *(const ushort8*)&X[(size_t)j0 * 128 + c8];
            ushort8 u1 = *(const ushort8*)&X[(size_t)j1 * 128 + c8];
#pragma unroll
            for (int j = 0; j < 8; ++j) acc[j] += bf2f(u0[j]) + bf2f(u1[j]);
        }
        if (i < s1) {
            int j0 = lst[i];
            ushort8 u0 = *(const ushort8*)&X[(size_t)j0 * 128 + c8];
#pragma unroll
            for (int j = 0; j < 8; ++j) acc[j] += bf2f(u0[j]);
        }
        ushort8 o;
        if (AFFINE) {
            float cf = (float)(dg + 1);
#pragma unroll
            for (int j = 0; j < 8; ++j)
                o[j] = f2bf(fmaf(Af[c8 + j], acc[j], cf * Bf[c8 + j]));
        } else {
#pragma unroll
            for (int j = 0; j < 8; ++j) o[j] = f2bf(acc[j]);
        }
        *(ushort8*)&out[(size_t)node * 128 + c8] = o;
    }
}

// ================= MFMA GEMM v3: Out = bf16(leaky(A @ W + bias)) ================
// Both tiles staged direct-to-LDS via global_load_lds width=16. XOR swizzle lives
// in the SOURCE address; LDS frag reads stay conflict-free. OOB rows -> zero pad.
template<bool STATS>
__global__ __launch_bounds__(256)
void gemm_mfma(const unsigned short* __restrict__ A, const unsigned short* __restrict__ WT,
               const float* __restrict__ bias, unsigned short* __restrict__ Out,
               float* __restrict__ stat_sum, float* __restrict__ stat_sq,
               const unsigned short* __restrict__ zeroPad, int N)
{
    __shared__ unsigned short As[128 * 128];  // 32 KB, slot (r,g'): holds chunk g'^(r&7)
    __shared__ unsigned short Ws[128 * 128];  // 32 KB
    __shared__ float sred[256];

    const int t = threadIdx.x;
    const int row0 = blockIdx.x * 128;

#pragma unroll
    for (int p = 0; p < 8; ++p) {
        int s  = p * 256 + t;          // LDS slot; per wave: uniform base + lane*16B
        int r  = s >> 4;
        int gp = s & 15;
        int g  = gp ^ (r & 7);         // source chunk for this slot
        int gr = row0 + r;
        const unsigned short* ga = (gr < N) ? &A[(size_t)gr * 128 + g * 8] : zeroPad;
        load_lds16(ga, &As[s * 8]);
        load_lds16(&WT[r * 128 + g * 8], &Ws[s * 8]);
    }
    __syncthreads();

    const int wave = t >> 6;
    const int lane = t & 63;
    const int m    = lane & 15;
    const int quad = lane >> 4;

    ffrag acc[2][8];
#pragma unroll
    for (int rt = 0; rt < 2; ++rt)
#pragma unroll
        for (int ct = 0; ct < 8; ++ct) {
            ffrag z = {0.f, 0.f, 0.f, 0.f};
            acc[rt][ct] = z;
        }

#pragma unroll
    for (int ks = 0; ks < 4; ++ks) {
        int kc = ks * 4 + quad;
        bfrag b[8];
#pragma unroll
        for (int ct = 0; ct < 8; ++ct) {
            int n = ct * 16 + m;
            b[ct] = *(const bfrag*)&Ws[(n * 16 + (kc ^ (n & 7))) * 8];
        }
        bfrag a0, a1;
        {
            int r = wave * 32 + m;
            a0 = *(const bfrag*)&As[(r * 16 + (kc ^ (r & 7))) * 8];
        }
        {
            int r = wave * 32 + 16 + m;
            a1 = *(const bfrag*)&As[(r * 16 + (kc ^ (r & 7))) * 8];
        }
#pragma unroll
        for (int ct = 0; ct < 8; ++ct) {
            acc[0][ct] = __builtin_amdgcn_mfma_f32_16x16x32_bf16(a0, b[ct], acc[0][ct], 0, 0, 0);
            acc[1][ct] = __builtin_amdgcn_mfma_f32_16x16x32_bf16(a1, b[ct], acc[1][ct], 0, 0, 0);
        }
    }

    float bv[8];
#pragma unroll
    for (int ct = 0; ct < 8; ++ct) bv[ct] = bias[ct * 16 + m];

    float colsum[8], colsq[8];
#pragma unroll
    for (int ct = 0; ct < 8; ++ct) { colsum[ct] = 0.f; colsq[ct] = 0.f; }

    __syncthreads();   // done with tiles; reuse As as transpose buffer
    unsigned short* tw = &As[wave * 32 * 128];   // this wave's 32x128 region
#pragma unroll
    for (int rt = 0; rt < 2; ++rt) {
#pragma unroll
        for (int reg = 0; reg < 4; ++reg) {
            int rl = rt * 16 + quad * 4 + reg;
            bool valid = (row0 + wave * 32 + rl) < N;
#pragma unroll
            for (int ct = 0; ct < 8; ++ct) {
                float v = leaky(acc[rt][ct][reg] + bv[ct]);
                tw[rl * 128 + ct * 16 + m] = f2bf(v);
                if (STATS && valid) { colsum[ct] += v; colsq[ct] += v * v; }
            }
        }
    }
    __syncthreads();
#pragma unroll
    for (int p = 0; p < 8; ++p) {
        int li = p * 64 + lane;        // 0..511 over this wave's region
        int rl = li >> 4;              // 0..31
        int cg = (li & 15) * 8;
        int r = row0 + wave * 32 + rl;
        if (r < N)
            *(ushort8*)&Out[(size_t)r * 128 + cg] = *(const ushort8*)&tw[rl * 128 + cg];
    }

    if (STATS) {
        __syncthreads();
        if (t < 128) { sred[t] = 0.f; sred[128 + t] = 0.f; }
        __syncthreads();
#pragma unroll
        for (int ct = 0; ct < 8; ++ct) {
            atomicAdd(&sred[ct * 16 + m], colsum[ct]);
            atomicAdd(&sred[128 + ct * 16 + m], colsq[ct]);
        }
        __syncthreads();
        if (t < 128) {
            atomicAdd(&stat_sum[t], sred[t]);
            atomicAdd(&stat_sq[t], sred[128 + t]);
        }
    }
}

// ================= pool + head (inline BN2 finalize) ============================
__device__ __forceinline__ int lower_bound(const int* b, int n, int v)
{
    int lo = 0, hi = n;
    while (lo < hi) { int mid = (lo + hi) >> 1; if (b[mid] < v) lo = mid + 1; else hi = mid; }
    return lo;
}

__global__ __launch_bounds__(128)
void pool_head(const unsigned short* __restrict__ Hn, const int* __restrict__ batch,
               const float* __restrict__ bnsum, const float* __restrict__ bnsq,
               const float* __restrict__ g2, const float* __restrict__ be2,
               const float* __restrict__ fcW1, const float* __restrict__ fcb1,
               const float* __restrict__ fcW2, const float* __restrict__ fcb2,
               float* __restrict__ out, int N)
{
    int g = blockIdx.x;
    int t = threadIdx.x;
    __shared__ int bounds[2];
    __shared__ float row[128];
    __shared__ float z1[128];
    if (t < 2) bounds[t] = lower_bound(batch, N, g + t);
    float invN = 1.f / (float)N;
    float mean = bnsum[t] * invN;
    float var  = bnsq[t] * invN - mean * mean;
    float a2 = g2[t] * rsqrtf(var + BN_EPS);
    float b2 = be2[t] - a2 * mean;
    __syncthreads();
    int ss = bounds[0], se = bounds[1];
    float acc = 0.f;
    for (int i = ss; i < se; ++i) acc += bf2f(Hn[(size_t)i * 128 + t]);
    float cnt = (float)(se - ss);
    row[t] = fmaf(a2, acc, cnt * b2);
    __syncthreads();
    float a1 = fcb1[t];
#pragma unroll 8
    for (int k = 0; k < 128; ++k) a1 = fmaf(row[k], fcW1[(size_t)k * 128 + t], a1);
    z1[t] = leaky(a1);
    __syncthreads();
    if (t < 64) {
        float lg[NCLS];
#pragma unroll
        for (int c = 0; c < NCLS; ++c) {
            float p = z1[t] * fcW2[t * NCLS + c] + z1[t + 64] * fcW2[(t + 64) * NCLS + c];
#pragma unroll
            for (int off = 32; off > 0; off >>= 1) p += __shfl_down(p, off, 64);
            if (t == 0) lg[c] = p + fcb2[c];
        }
        if (t == 0) {
            float m = lg[0];
#pragma unroll
            for (int c = 1; c < NCLS; ++c) m = fmaxf(m, lg[c]);
            float s = 0.f;
#pragma unroll
            for (int c = 0; c < NCLS; ++c) s += expf(lg[c] - m);
            float lse = logf(s);
#pragma unroll
            for (int c = 0; c < NCLS; ++c) out[(size_t)g * NCLS + c] = lg[c] - m - lse;
        }
    }
}

// ================= launch =======================================================
extern "C" void kernel_launch(void* const* d_in, const int* in_sizes, int n_in,
                              void* d_out, int out_size, void* d_ws, size_t ws_size,
                              hipStream_t stream)
{
    const float* x    = (const float*)d_in[0];
    const float* W1a  = (const float*)d_in[1];
    const float* b1a  = (const float*)d_in[2];
    const float* W1b  = (const float*)d_in[3];
    const float* b1b  = (const float*)d_in[4];
    const float* g1   = (const float*)d_in[5];
    const float* be1  = (const float*)d_in[6];
    const float* W2a  = (const float*)d_in[7];
    const float* b2a  = (const float*)d_in[8];
    const float* W2b  = (const float*)d_in[9];
    const float* b2b  = (const float*)d_in[10];
    const float* g2   = (const float*)d_in[11];
    const float* be2  = (const float*)d_in[12];
    const float* fcW1 = (const float*)d_in[13];
    const float* fcb1 = (const float*)d_in[14];
    const float* fcW2 = (const float*)d_in[15];
    const float* fcb2 = (const float*)d_in[16];
    const int*   edge = (const int*)d_in[17];
    const int*   batch= (const int*)d_in[18];

    const int N = in_sizes[0] / 128;
    const int E = in_sizes[17] / 2;
    const int* src = edge;
    const int* dst = edge + E;
    const size_t NH = (size_t)N * 128;
    const int NB = (N + WN - 1) / WN;       // 64-node windows (<= NBMAX)
    const int chunk = (E + PB - 1) / PB;

    // ---- workspace layout (all big buffers 64B-aligned: offsets are multiples
    //      of 64B; bug in R9 had packedE at +32B -> 5-line rows, +43% gather FETCH)
    int*   cursor = (int*)d_ws;                     // 2048 ints  (8192 B)
    float* stats  = (float*)(cursor + 2048);        // 512 floats
    float* sum1   = stats;
    float* sq1    = stats + 128;
    float* sum2   = stats + 256;
    float* sq2    = stats + 384;
    unsigned short* zeroPad = (unsigned short*)(stats + 512);  // 512 B zero region
    int*   packedE = (int*)(stats + 640);           // byte 10752, 64B-aligned
    unsigned short* xb   = (unsigned short*)(packedE + ((size_t)NBMAX * CAP));
    unsigned short* bufA = xb + NH;
    unsigned short* bufB = bufA + NH;
    unsigned short* wt   = bufB + NH;               // 4 x 16384 bf16, transposed
    unsigned short* wt1a = wt;
    unsigned short* wt1b = wt + 16384;
    unsigned short* wt2a = wt + 32768;
    unsigned short* wt2b = wt + 49152;

    const int cvtBlocks  = (int)((NH / 4 + 255) / 256);
    const int gemmBlocks = (N + 127) / 128;

    hipMemsetAsync(d_ws, 0, 2048 * sizeof(int) + 640 * sizeof(float), stream);

    // fused: window-sort edges + x/weight bf16 conversion
    scatter_cvt_kernel<<<PB + 4 + cvtBlocks, 256, 0, stream>>>(
        src, dst, cursor, packedE, E, chunk, NB,
        x, xb, (int)NH, W1a, W1b, W2a, W2b, wt);

    // conv1
    gather_win<false><<<NB * 2, 256, 0, stream>>>(xb, cursor, packedE,
                                                  nullptr, nullptr, nullptr, nullptr, bufA, N);
    gemm_mfma<false><<<gemmBlocks, 256, 0, stream>>>(bufA, wt1a, b1a, bufB,
                                                     nullptr, nullptr, zeroPad, N);
    gemm_mfma<true><<<gemmBlocks, 256, 0, stream>>>(bufB, wt1b, b1b, bufA,
                                                    sum1, sq1, zeroPad, N);

    // conv2 (BN1 finalized inline in gather epilogue)
    gather_win<true><<<NB * 2, 256, 0, stream>>>(bufA, cursor, packedE,
                                                 sum1, sq1, g1, be1, bufB, N);
    gemm_mfma<false><<<gemmBlocks, 256, 0, stream>>>(bufB, wt2a, b2a, bufA,
                                                     nullptr, nullptr, zeroPad, N);
    gemm_mfma<true><<<gemmBlocks, 256, 0, stream>>>(bufA, wt2b, b2b, bufB,
                                                    sum2, sq2, zeroPad, N);

    // pool (BN2 finalized inline) + head
    pool_head<<<NUM_GRAPHS, 128, 0, stream>>>(bufB, batch, sum2, sq2, g2, be2,
                                              fcW1, fcb1, fcW2, fcb2, (float*)d_out, N);
}